// Round 4
// baseline (267.015 us; speedup 1.0000x reference)
//
#include <hip/hip_runtime.h>
#include <stdint.h>
#include <math.h>

// Problem geometry (B=32, C=384, H=W=56), float32 in/out.
#define TOTAL_N 38535168   // 32*384*56*56
#define HW_SZ   3136       // 56*56  (multiple of 8 -> 8 consecutive elems share a channel)
#define NCH     384

// Single-instruction rotate: v_alignbit_b32(x,x,32-r) == rotl(x,r)
__device__ __forceinline__ uint32_t rotl32(uint32_t x, int r) {
  return __builtin_amdgcn_alignbit(x, x, 32 - r);
}

// ---------------------------------------------------------------------------
// JAX partitionable threefry (default since 0.4.30), verified bit-exact R3:
//   bits[i] = o0 ^ o1, (o0,o1) = threefry2x32(key=(0,42), counter=(0, i))
// ---------------------------------------------------------------------------
__device__ __forceinline__ uint32_t tf_bits(uint32_t i) {
  const uint32_t ks0 = 0u;
  const uint32_t ks1 = 42u;
  const uint32_t ks2 = 0x1BD11BDAu ^ 0u ^ 42u;  // 0x1BD11BF0

  uint32_t x0 = 0u + ks0;   // counter_hi + ks[0]
  uint32_t x1 = i + ks1;    // counter_lo + ks[1]

#define TF_R(r) { x0 += x1; x1 = rotl32(x1, (r)) ^ x0; }
  TF_R(13) TF_R(15) TF_R(26) TF_R(6)
  x0 += ks1; x1 += ks2 + 1u;
  TF_R(17) TF_R(29) TF_R(16) TF_R(24)
  x0 += ks2; x1 += ks0 + 2u;
  TF_R(13) TF_R(15) TF_R(26) TF_R(6)
  x0 += ks0; x1 += ks1 + 3u;
  TF_R(17) TF_R(29) TF_R(16) TF_R(24)
  x0 += ks1; x1 += ks2 + 4u;
  TF_R(13) TF_R(15) TF_R(26) TF_R(6)
  x0 += ks2; x1 += ks0 + 5u;
#undef TF_R

  return x0 ^ x1;
}

// ---------------------------------------------------------------------------
// Prep: keep_prob[c] computed in exact reference rounding order, then folded
// into a pure-integer threshold:
//   u = (bits>>9)/2^23 exactly (1.m - 1.0 is exact in [1,2))
//   u < kp  <=>  (bits>>9) < ceil(kp*2^23)  <=>  bits < ceil(kp*2^23)<<9
// ceil(kp*2^23) computed in double (exact: 24-bit mantissa * 2^23).
// ---------------------------------------------------------------------------
__global__ __launch_bounds__(64) void prep_thresholds(
    const float* __restrict__ fi, uint32_t* __restrict__ thr9) {
  int t = threadIdx.x;  // 0..63
  float mn = fi[t];
  float mx = mn;
  for (int c = t + 64; c < NCH; c += 64) {
    float v = fi[c];
    mn = fminf(mn, v);
    mx = fmaxf(mx, v);
  }
  for (int off = 1; off < 64; off <<= 1) {
    mn = fminf(mn, __shfl_xor(mn, off));
    mx = fmaxf(mx, __shfl_xor(mx, off));
  }
  float denom = __fsub_rn(mx, mn);
  for (int c = t; c < NCH; c += 64) {
    float scaled = __fdiv_rn(__fsub_rn(fi[c], mn), denom);
    float one_minus = __fsub_rn(1.0f, scaled);
    float rates = __fadd_rn(0.1f, __fmul_rn(0.4f, one_minus));
    float kp = __fsub_rn(1.0f, rates);  // reference rounding order
    uint32_t thr = (uint32_t)ceil((double)kp * 8388608.0);  // exact in double
    thr9[c] = thr << 9;  // kp<=0.9 -> thr<=0.9*2^23, no overflow
  }
}

// ---------------------------------------------------------------------------
// Main: 8 consecutive elements per thread (two float4 loads/stores).
// HW_SZ % 8 == 0 -> all 8 share one channel. Pure-integer mask test.
// ---------------------------------------------------------------------------
__global__ __launch_bounds__(256) void dropout_kernel(
    const float* __restrict__ x, const uint32_t* __restrict__ thr9,
    float* __restrict__ out) {
  int tid = blockIdx.x * 256 + threadIdx.x;
  int i0 = tid << 3;
  if (i0 >= TOTAL_N) return;

  uint32_t thr = thr9[(i0 / HW_SZ) % NCH];

  float4 xa = *reinterpret_cast<const float4*>(x + i0);
  float4 xb = *reinterpret_cast<const float4*>(x + i0 + 4);
  float4 oa, ob;

  oa.x = (tf_bits(i0 + 0) < thr) ? xa.x : 0.0f;
  oa.y = (tf_bits(i0 + 1) < thr) ? xa.y : 0.0f;
  oa.z = (tf_bits(i0 + 2) < thr) ? xa.z : 0.0f;
  oa.w = (tf_bits(i0 + 3) < thr) ? xa.w : 0.0f;
  ob.x = (tf_bits(i0 + 4) < thr) ? xb.x : 0.0f;
  ob.y = (tf_bits(i0 + 5) < thr) ? xb.y : 0.0f;
  ob.z = (tf_bits(i0 + 6) < thr) ? xb.z : 0.0f;
  ob.w = (tf_bits(i0 + 7) < thr) ? xb.w : 0.0f;

  *reinterpret_cast<float4*>(out + i0) = oa;
  *reinterpret_cast<float4*>(out + i0 + 4) = ob;
}

extern "C" void kernel_launch(void* const* d_in, const int* in_sizes, int n_in,
                              void* d_out, int out_size, void* d_ws, size_t ws_size,
                              hipStream_t stream) {
  const float* x = (const float*)d_in[0];
  const float* fi = (const float*)d_in[1];
  float* out = (float*)d_out;
  uint32_t* thr9 = (uint32_t*)d_ws;  // 384 u32 of scratch

  prep_thresholds<<<1, 64, 0, stream>>>(fi, thr9);

  const int threads_total = TOTAL_N / 8;           // 4,816,896
  const int blocks = threads_total / 256;          // 18,816 (exact)
  dropout_kernel<<<blocks, 256, 0, stream>>>(x, thr9, out);
}